// Round 1
// baseline (259.531 us; speedup 1.0000x reference)
//
#include <hip/hip_runtime.h>
#include <hip/hip_bf16.h>

typedef __bf16 bf16x8 __attribute__((ext_vector_type(8)));
typedef unsigned short u16x8 __attribute__((ext_vector_type(8)));
typedef float f32x4 __attribute__((ext_vector_type(4)));

// ---------------------------------------------------------------------------
// Prep: pack W1 [1280x32] and W2 [32x128] (f32, row-major) into bf16 MFMA
// B-fragment order for mfma_f32_16x16x32_bf16.
// Fragment element (lane l, elem j) <- W[k = kt*32 + (l>>4)*8 + j][n = nt*16 + (l&15)]
// (the (l>>4,j)->k bijection is chosen; it cancels against the A-side packing)
// wsB1[((kt*2+nt)*64 + l)*8 + j], wsB2[((nt)*64 + l)*8 + j]
// ---------------------------------------------------------------------------
__global__ __launch_bounds__(256) void prep_w_kernel(
    const float* __restrict__ W1, const float* __restrict__ W2,
    unsigned short* __restrict__ wsB1, unsigned short* __restrict__ wsB2) {
  int tid = blockIdx.x * 256 + threadIdx.x;
  if (tid < 40960) {                      // W1 frags: 40 ktiles * 2 ntiles * 512
    int j = tid & 7, l = (tid >> 3) & 63, nt = (tid >> 9) & 1, kt = tid >> 10;
    int k = kt * 32 + ((l >> 4) << 3) + j;
    int n = nt * 16 + (l & 15);
    __bf16 v = (__bf16)W1[k * 32 + n];
    wsB1[tid] = __builtin_bit_cast(unsigned short, v);
  } else if (tid < 45056) {               // W2 frags: 8 ntiles * 512
    int t = tid - 40960;
    int j = t & 7, l = (t >> 3) & 63, nt = t >> 9;
    int k = ((l >> 4) << 3) + j;
    int n = nt * 16 + (l & 15);
    __bf16 v = (__bf16)W2[k * 128 + n];
    wsB2[t] = __builtin_bit_cast(unsigned short, v);
  }
}

// ---------------------------------------------------------------------------
// Main: one wave handles a strip of 16 edges.
// GEMM1: h[16][32] = elu(x[16][1280] @ W1 + b1)  (40 ktiles x 2 ntiles MFMA)
// transpose h via LDS (C-layout -> A-layout), GEMM2: out[16][128] = h @ W2 + b2
// ---------------------------------------------------------------------------
template <bool USE_WS>
__global__ __launch_bounds__(256) void edge_mlp_kernel(
    const float* __restrict__ src, const float* __restrict__ dst,
    const float* __restrict__ ea, const float* __restrict__ W1,
    const float* __restrict__ b1, const float* __restrict__ W2,
    const float* __restrict__ b2, const unsigned short* __restrict__ wsB1,
    const unsigned short* __restrict__ wsB2, float* __restrict__ out, int nE) {
  __shared__ alignas(16) unsigned short hbuf_s[4][16 * 40];  // 40 = padded row stride
  const int lane = threadIdx.x & 63;
  const int wave = threadIdx.x >> 6;
  const int l15 = lane & 15;
  const int lh = lane >> 4;
  const long strip = (long)blockIdx.x * 4 + wave;
  const long e0 = strip * 16;
  if (e0 >= nE) return;
  long row = e0 + l15;
  if (row >= nE) row = nE - 1;  // clamp; stores for OOB edges are predicated

  f32x4 acc0 = {0.f, 0.f, 0.f, 0.f};
  f32x4 acc1 = {0.f, 0.f, 0.f, 0.f};

  auto do_tile = [&](const float* p, int kt) {
    f32x4 lo = *(const f32x4*)p;          // 8 contiguous f32 of this row
    f32x4 hi = *(const f32x4*)(p + 4);
    bf16x8 a;
    a[0] = (__bf16)lo[0]; a[1] = (__bf16)lo[1];
    a[2] = (__bf16)lo[2]; a[3] = (__bf16)lo[3];
    a[4] = (__bf16)hi[0]; a[5] = (__bf16)hi[1];
    a[6] = (__bf16)hi[2]; a[7] = (__bf16)hi[3];
    bf16x8 bf0, bf1;
    if (USE_WS) {
      const unsigned short* wp = wsB1 + kt * 1024 + lane * 8;
      bf0 = __builtin_bit_cast(bf16x8, *(const u16x8*)wp);
      bf1 = __builtin_bit_cast(bf16x8, *(const u16x8*)(wp + 512));
    } else {
#pragma unroll
      for (int j = 0; j < 8; ++j) {
        int k = kt * 32 + lh * 8 + j;
        bf0[j] = (__bf16)W1[k * 32 + l15];
        bf1[j] = (__bf16)W1[k * 32 + 16 + l15];
      }
    }
    acc0 = __builtin_amdgcn_mfma_f32_16x16x32_bf16(a, bf0, acc0, 0, 0, 0);
    acc1 = __builtin_amdgcn_mfma_f32_16x16x32_bf16(a, bf1, acc1, 0, 0, 0);
  };

  {
    const float* base = src + row * 512 + lh * 8;
#pragma unroll 4
    for (int kt = 0; kt < 16; ++kt) do_tile(base + kt * 32, kt);
  }
  {
    const float* base = dst + row * 512 + lh * 8;
#pragma unroll 4
    for (int kt = 0; kt < 16; ++kt) do_tile(base + kt * 32, 16 + kt);
  }
  {
    const float* base = ea + row * 256 + lh * 8;
#pragma unroll 4
    for (int kt = 0; kt < 8; ++kt) do_tile(base + kt * 32, 32 + kt);
  }

  // ---- bias + ELU, write h (bf16) to LDS in C-layout positions ----
  const float bias0 = b1[l15];
  const float bias1 = b1[16 + l15];
  unsigned short* hl = hbuf_s[wave];
#pragma unroll
  for (int r = 0; r < 4; ++r) {
    int hrow = lh * 4 + r;  // C/D layout: row=(lane>>4)*4+reg, col=lane&15
    float h0 = acc0[r] + bias0;
    float h1 = acc1[r] + bias1;
    h0 = h0 > 0.f ? h0 : (__expf(h0) - 1.f);
    h1 = h1 > 0.f ? h1 : (__expf(h1) - 1.f);
    __bf16 v0 = (__bf16)h0, v1 = (__bf16)h1;
    hl[hrow * 40 + l15] = __builtin_bit_cast(unsigned short, v0);
    hl[hrow * 40 + 16 + l15] = __builtin_bit_cast(unsigned short, v1);
  }
  // wave-local: all lanes' ds_writes precede this in program order; drain them
  asm volatile("s_waitcnt lgkmcnt(0)" ::: "memory");
  // read back in A-fragment layout: lane l -> h[l&15][(l>>4)*8 + j]
  bf16x8 ha =
      __builtin_bit_cast(bf16x8, *(const u16x8*)(hl + l15 * 40 + lh * 8));

  // ---- GEMM2: out tiles over 8 ntiles of 16 cols ----
  f32x4 o[8];
#pragma unroll
  for (int nt = 0; nt < 8; ++nt) {
    bf16x8 bw;
    if (USE_WS) {
      bw = __builtin_bit_cast(bf16x8, *(const u16x8*)(wsB2 + nt * 512 + lane * 8));
    } else {
#pragma unroll
      for (int j = 0; j < 8; ++j)
        bw[j] = (__bf16)W2[(lh * 8 + j) * 128 + nt * 16 + l15];
    }
    f32x4 z = {0.f, 0.f, 0.f, 0.f};
    o[nt] = __builtin_amdgcn_mfma_f32_16x16x32_bf16(ha, bw, z, 0, 0, 0);
  }

#pragma unroll
  for (int nt = 0; nt < 8; ++nt) {
    float bb = b2[nt * 16 + l15];
#pragma unroll
    for (int r = 0; r < 4; ++r) {
      long e = e0 + lh * 4 + r;
      if (e < nE) out[e * 128 + nt * 16 + l15] = o[nt][r] + bb;
    }
  }
}

extern "C" void kernel_launch(void* const* d_in, const int* in_sizes, int n_in,
                              void* d_out, int out_size, void* d_ws,
                              size_t ws_size, hipStream_t stream) {
  const float* src = (const float*)d_in[0];
  const float* dst = (const float*)d_in[1];
  const float* ea = (const float*)d_in[2];
  // d_in[3] = u (unused), d_in[4] = batch (unused)
  const float* W1 = (const float*)d_in[5];
  const float* b1 = (const float*)d_in[6];
  const float* W2 = (const float*)d_in[7];
  const float* b2 = (const float*)d_in[8];
  float* out = (float*)d_out;

  const int nE = in_sizes[0] / 512;           // 200000
  const long strips = (nE + 15) / 16;         // 12500
  const int nblocks = (int)((strips + 3) / 4);  // 3125

  unsigned short* wsB1 = (unsigned short*)d_ws;
  unsigned short* wsB2 = wsB1 + 40960;
  const bool use_ws = ws_size >= 45056 * sizeof(unsigned short);

  if (use_ws) {
    prep_w_kernel<<<176, 256, 0, stream>>>(W1, W2, wsB1, wsB2);
    edge_mlp_kernel<true><<<nblocks, 256, 0, stream>>>(
        src, dst, ea, W1, b1, W2, b2, wsB1, wsB2, out, nE);
  } else {
    edge_mlp_kernel<false><<<nblocks, 256, 0, stream>>>(
        src, dst, ea, W1, b1, W2, b2, nullptr, nullptr, out, nE);
  }
}